// Round 10
// baseline (117.714 us; speedup 1.0000x reference)
//
#include <hip/hip_runtime.h>
#include <math.h>

// ---------------------------------------------------------------------------
// HyperbolicInfoNCE on MI355X — Round 16: in-loop atomics -> LDS, end-batch
// drain. Single-variable ablation on R14.
//
// R15 post-mortem: occupancy law SATURATES at ~12 waves/CU — R10/R14/R15
// all 48.3-48.8us despite different residency. The remaining ~23us stall
// (wall 48.5 vs 25.6us VALU-issue floor) is CORRELATED across waves: all
// wait together at the per-tile barrier. The barrier's vmcnt(0) drain waits
// on this phase's 4 global atomicAdds to colRep — contended RMWs (16 blocks
// x 4 waves on the same 64-address set, ~2-4Kcyc serialized) paid at every
// one of the 8 barriers. R12's apparent exoneration of in-loop atomics was
// confounded by its [col][4] same-cacheline end drain (its 55.4us and 22.8%
// occupancy are fully explained by that bug's serialized tail).
//
// R16 = R14 with ONE change: col partials accumulate in LDS colAcc[512]
// (ds_add, lgkm-tracked, no L2 RMW) and drain to the separated replica
// arrays ONCE per block at kernel end, fire-and-forget. In-loop barrier now
// drains only stage loads (issued a phase earlier, long complete). Grid,
// block geometry, Ah hoist, STAGE/COMPUTE, convert, finalize: identical.
// Decisive split: dur -> 32-38us confirms atomic-drain theory; dur ~48
// refutes it -> next lever is counted-vmcnt raw barriers (T4).
// ---------------------------------------------------------------------------

#define BDIM   8192
#define K_IN   129
#define K_PAD  160      // 5 * 32
#define BK     32
#define NKT    5        // k-tiles of 32
#define CTILES 8        // 64-col tiles per block (128 rows x 512 cols)

typedef __bf16  bf16x8 __attribute__((ext_vector_type(8)));
typedef float   f32x4  __attribute__((ext_vector_type(4)));
typedef unsigned short u16x4 __attribute__((ext_vector_type(4)));

// ws layout (bytes)
#define OFF_A    0u
#define OFF_B    (BDIM * K_PAD * 2u)                  // 2,621,440
#define OFF_RS   (2u * BDIM * K_PAD * 2u)             // 5,242,880
#define OFF_CP   (OFF_RS + BDIM * 4u)                 // 4 separated col replicas
#define OFF_DG   (OFF_CP + 4u * BDIM * 4u)

// ---- hardware transcendentals (v_sqrt_f32 / v_log_f32 / v_exp_f32) ----
__device__ __forceinline__ float fast_sqrt(float x) {
#if __has_builtin(__builtin_amdgcn_sqrtf)
    return __builtin_amdgcn_sqrtf(x);
#else
    return sqrtf(x);
#endif
}
__device__ __forceinline__ float fast_log2(float x) {
#if __has_builtin(__builtin_amdgcn_logf)
    return __builtin_amdgcn_logf(x);       // log base 2
#else
    return __log2f(x);
#endif
}
__device__ __forceinline__ float fast_exp2(float x) {
#if __has_builtin(__builtin_amdgcn_exp2f)
    return __builtin_amdgcn_exp2f(x);      // 2^x
#else
    extern "C" __device__ float __ocml_native_exp2_f32(float);
    return __ocml_native_exp2_f32(x);
#endif
}

__device__ __forceinline__ unsigned short f2bf_rne(float f) {
    unsigned int u = __float_as_uint(f);
    u += 0x7FFFu + ((u >> 16) & 1u);   // round-to-nearest-even
    return (unsigned short)(u >> 16);
}

// ---------------------------------------------------------------------------
// Kernel 1: fp32 -> bf16, float4-granular: thread handles 4 consecutive
// elements. K zero-padded 129->160, Lorentz metric folded into A (negate
// col 0). Also zeroes row_sum + 4 col replicas.
// ---------------------------------------------------------------------------
__global__ __launch_bounds__(256) void convert_kernel(
    const float* __restrict__ z1, const float* __restrict__ z2,
    unsigned short* __restrict__ A, unsigned short* __restrict__ B,
    float* __restrict__ rs_cp)
{
    int v = blockIdx.x * 256 + threadIdx.x;
    if (v < 5 * BDIM) rs_cp[v] = 0.f;          // rs (8192) + cp (4*8192)
    if (v >= BDIM * (K_PAD / 4)) return;
    int r  = v / (K_PAD / 4);
    int c4 = (v - r * (K_PAD / 4)) * 4;
    u16x4 a, b;
    #pragma unroll
    for (int i = 0; i < 4; ++i) {
        int c = c4 + i;
        float va = 0.f, vb = 0.f;
        if (c < K_IN) {
            va = z1[r * K_IN + c];
            vb = z2[r * K_IN + c];
            if (c == 0) va = -va;              // Lorentz metric on coord 0
        }
        a[i] = f2bf_rne(va);
        b[i] = f2bf_rne(vb);
    }
    *(u16x4*)(A + r * K_PAD + c4) = a;
    *(u16x4*)(B + r * K_PAD + c4) = b;
}

// ---------------------------------------------------------------------------
// Kernel 2: strip-GEMM with fused acosh/exp epilogue; B staged through a
// double-buffered LDS pipeline (global_load_lds); col sums in LDS, drained
// once at kernel end.
//   grid = 1024: bid = chunk*64 + strip  (consecutive blocks share B-chunk)
//   block: rows [strip*128, +128) x cols [chunk*512, +512), 8 tiles of 64
//   wave w (0..3): rows [strip*128 + w*32, +32)
//   fragment layouts (guide-verified, m89/m91):
//     A/B operand: elem [m=lane&15][k=(lane>>4)*8 + j]
//     C/D:         elem [row=(lane>>4)*4 + reg][col=lane&15]
// ---------------------------------------------------------------------------

// Stage one 64-col B-tile (20KB contiguous global chunk) into Bs[bufidx].
// Each wave issues 5 async 1KB copies; LDS dest wave-uniform + lane*16 (m104).
#define STAGE(bufidx, cb)                                                     \
    {                                                                         \
        const char* _gp = (const char*)(B + (size_t)(cb) * K_PAD)             \
                          + wave * 5120 + lane * 16;                          \
        unsigned short* _lp = &Bs[bufidx][wave * 2560];                       \
        _Pragma("unroll")                                                     \
        for (int _i = 0; _i < 5; ++_i)                                        \
            __builtin_amdgcn_global_load_lds(                                 \
                (const __attribute__((address_space(1))) void*)               \
                    (_gp + _i * 1024),                                        \
                (__attribute__((address_space(3))) void*)(_lp + _i * 512),    \
                16, 0, 0);                                                    \
    }

// MFMA + fused epilogue for one 32x64 wave-tile read from Bs[bufidx].
// Col partials -> LDS colAcc (ds_add); NO global memory ops added to the
// barrier's vmcnt queue.
#define COMPUTE(bufidx, cb)                                                   \
    {                                                                         \
        const int colBase = (cb);                                             \
        const unsigned short* _Bt = &Bs[bufidx][0];                           \
        f32x4 acc[2][4] = {};                                                 \
        _Pragma("unroll")                                                     \
        for (int kt = 0; kt < NKT; ++kt) {                                    \
            bf16x8 bfr[4];                                                    \
            _Pragma("unroll")                                                 \
            for (int j = 0; j < 4; ++j)                                       \
                bfr[j] = *(const bf16x8*)                                     \
                    &_Bt[(l16 + j * 16) * K_PAD + quad * 8 + kt * BK];        \
            _Pragma("unroll")                                                 \
            for (int i = 0; i < 2; ++i)                                       \
                _Pragma("unroll")                                             \
                for (int j = 0; j < 4; ++j)                                   \
                    acc[i][j] = __builtin_amdgcn_mfma_f32_16x16x32_bf16(      \
                        Ah[i][kt], bfr[j], acc[i][j], 0, 0, 0);               \
        }                                                                     \
        const bool diagTile = (colBase == (rowBase & ~63));                   \
        const int  dj       = (rowBase >> 4) & 2;                             \
        float colp[4] = {0.f, 0.f, 0.f, 0.f};                                 \
        _Pragma("unroll")                                                     \
        for (int i = 0; i < 2; ++i) {                                         \
            _Pragma("unroll")                                                 \
            for (int j = 0; j < 4; ++j) {                                     \
                _Pragma("unroll")                                             \
                for (int reg = 0; reg < 4; ++reg) {                           \
                    float inner = acc[i][j][reg];                             \
                    float x = fmaxf(-inner, 1.000001f);                       \
                    float s = fast_sqrt(__builtin_fmaf(x, x, -1.0f));         \
                    float l2u = fast_log2(x + s);                             \
                    float e = fast_exp2(-14.285714285714286f * l2u);          \
                    rowp[i][reg] += e;                                        \
                    colp[j]      += e;                                        \
                    if (diagTile && (j - i) == dj && (quad * 4 + reg) == l16){\
                        int R = rowBase + i * 16 + quad * 4 + reg;            \
                        diag[R] = -9.902102579427789f * l2u;                  \
                    }                                                         \
                }                                                             \
            }                                                                 \
        }                                                                     \
        _Pragma("unroll")                                                     \
        for (int j = 0; j < 4; ++j) {                                         \
            float v = colp[j];                                                \
            v += __shfl_xor(v, 16);                                           \
            v += __shfl_xor(v, 32);                                           \
            if (quad == 0)                                                    \
                atomicAdd(&colAcc[(colBase - colChunk) + j * 16 + l16], v);   \
        }                                                                     \
    }

__global__ __launch_bounds__(256, 4) void gemm_epilogue_kernel(
    const unsigned short* __restrict__ A, const unsigned short* __restrict__ B,
    float* __restrict__ row_sum, float* __restrict__ col_part,
    float* __restrict__ diag)
{
    const int t    = threadIdx.x;
    const int lane = t & 63;
    const int wave = t >> 6;
    const int quad = lane >> 4;
    const int l16  = lane & 15;

    const int strip = blockIdx.x & 63;
    const int chunk = blockIdx.x >> 6;                // 0..15
    const int rowBase  = strip * 128 + wave * 32;     // wave's first row
    const int colChunk = chunk * 512;                 // block's first col

    const unsigned short* Abase = A + (rowBase + l16) * K_PAD + quad * 8;

    // B-tile double buffer + block col accumulator (LDS atomics in-loop,
    // drained to global replicas ONCE at kernel end, fire-and-forget).
    __shared__ __align__(16) unsigned short Bs[2][64 * K_PAD];
    __shared__ float colAcc[512];

    for (int c = t; c < 512; c += 256) colAcc[c] = 0.f;

    // ---- hoist the entire A operand for this wave: 2 row-frags x 5 k-tiles
    bf16x8 Ah[2][NKT];
    #pragma unroll
    for (int i = 0; i < 2; ++i)
        #pragma unroll
        for (int kt = 0; kt < NKT; ++kt)
            Ah[i][kt] = *(const bf16x8*)(Abase + i * 16 * K_PAD + kt * BK);

    float rowp[2][4] = {};   // persistent across all col-tiles

    // ---- 2-phase pipeline: stage next tile, compute current, one barrier
    STAGE(0, colChunk);                  // prologue: tile 0 -> Bs[0]
    __syncthreads();                     // also covers colAcc zeroing

    #pragma unroll 1
    for (int ct = 0; ct < CTILES; ++ct) {
        if (ct + 1 < CTILES)
            STAGE((ct + 1) & 1, colChunk + (ct + 1) * 64);
        COMPUTE(ct & 1, colChunk + ct * 64);
        __syncthreads();                 // drains stage loads (long done) + ds_adds
    }

    // ---- epilogue: ALL global atomics batched here, fire-and-forget ----
    // row sums: reduce across the 16 lanes of each quad (they hold cols)
    #pragma unroll
    for (int i = 0; i < 2; ++i) {
        #pragma unroll
        for (int reg = 0; reg < 4; ++reg) {
            float v = rowp[i][reg];
            v += __shfl_xor(v, 1);
            v += __shfl_xor(v, 2);
            v += __shfl_xor(v, 4);
            v += __shfl_xor(v, 8);
            if (l16 == 0)
                atomicAdd(&row_sum[rowBase + i * 16 + quad * 4 + reg], v);
        }
    }
    // col sums: one atomic per col per block to SEPARATED replica arrays
    // (16 contenders per address, once per kernel). Last loop barrier
    // ordered all ds_adds before these reads.
    const int rep = strip & 3;
    for (int c = t; c < 512; c += 256)
        atomicAdd(&col_part[rep * BDIM + colChunk + c], colAcc[c]);
}

// ---------------------------------------------------------------------------
// Kernel 3: loss = mean_b( 0.5*(ln rs[b] + ln cs[b]) - diag[b] ),
// cs[b] = sum of 4 separated replicas.
// ---------------------------------------------------------------------------
__global__ __launch_bounds__(1024) void finalize_kernel(
    const float* __restrict__ rs, const float* __restrict__ cp,
    const float* __restrict__ dg, float* __restrict__ out)
{
    __shared__ float part[16];
    int t = threadIdx.x;
    float a = 0.f;
    const float LN2_HALF = 0.34657359027997264f;  // 0.5 * ln2
    for (int b = t; b < BDIM; b += 1024) {
        float cs = cp[b] + cp[b + BDIM] + cp[b + 2 * BDIM] + cp[b + 3 * BDIM];
        a += LN2_HALF * (fast_log2(rs[b]) + fast_log2(cs)) - dg[b];
    }
    #pragma unroll
    for (int m = 1; m < 64; m <<= 1) a += __shfl_xor(a, m);
    if ((t & 63) == 0) part[t >> 6] = a;
    __syncthreads();
    if (t < 16) {
        float v = part[t];
        #pragma unroll
        for (int m = 1; m < 16; m <<= 1) v += __shfl_xor(v, m);
        if (t == 0) out[0] = v * (1.0f / (float)BDIM);
    }
}

// ---------------------------------------------------------------------------
extern "C" void kernel_launch(void* const* d_in, const int* in_sizes, int n_in,
                              void* d_out, int out_size, void* d_ws, size_t ws_size,
                              hipStream_t stream)
{
    const float* z1 = (const float*)d_in[0];
    const float* z2 = (const float*)d_in[1];
    float* out = (float*)d_out;

    char* ws = (char*)d_ws;
    unsigned short* A  = (unsigned short*)(ws + OFF_A);
    unsigned short* B  = (unsigned short*)(ws + OFF_B);
    float* row_sum     = (float*)(ws + OFF_RS);
    float* col_part    = (float*)(ws + OFF_CP);
    float* diag        = (float*)(ws + OFF_DG);

    convert_kernel<<<(BDIM * (K_PAD / 4) + 255) / 256, 256, 0, stream>>>(
        z1, z2, A, B, row_sum /* rs + 4 separated col replicas contiguous */);

    gemm_epilogue_kernel<<<1024, 256, 0, stream>>>(
        A, B, row_sum, col_part, diag);

    finalize_kernel<<<1, 1024, 0, stream>>>(row_sum, col_part, diag, out);
}

// Round 11
// 117.479 us; speedup vs baseline: 1.0020x; 1.0020x over previous
//
#include <hip/hip_runtime.h>
#include <math.h>

// ---------------------------------------------------------------------------
// HyperbolicInfoNCE on MI355X — Round 17: BARRIER-FREE wave-private pipeline.
//
// R16 post-mortem: removing in-loop global atomics REGRESSED (48.5->56.0) —
// atomics exonerated with data. The ~23us gap above the 25.6us VALU-issue
// floor survives occupancy (12->16 waves: nil), atomics (nil/worse), LDS
// stride (nil). Common to all variants: __syncthreads every tile. The
// barrier re-couples all 4 waves 8x/kernel; its vmcnt(0)+wait re-exposes
// every wave's skew+latency as block-wide dead time (m233's lesson: in a
// 2-phase barrier loop, stage+drain+barrier IS the critical path).
//
// R17: make the B-tile WAVE-PRIVATE (16 cols x 160k x 2 bufs = 10,240B per
// wave; 40,960B per 4-wave block = same LDS, 3 blocks/CU). global_load_lds
// is tracked by the issuing wave's own vmcnt -> per-wave T4 pipeline:
//   issue 5 stage loads (tile ct+1) -> s_waitcnt vmcnt(5) (tile ct's loads,
//   issued a full phase ago, drained; ct+1's stay in flight) ->
//   sched_barrier(0) (rule #18) -> ds_read + 10 MFMA + 480cyc epilogue.
// ZERO __syncthreads. Waves fully decoupled; 3 waves/SIMD interleave with
// no correlated wait points. Cost: 4x B-stage duplication = L2 reads only
// (HBM FETCH unchanged — checkable). Grid/tiling/atomics/convert/finalize
// = R14 verbatim; per-lane summation order unchanged.
// ---------------------------------------------------------------------------

#define BDIM   8192
#define K_IN   129
#define K_PAD  160      // 5 * 32
#define BK     32
#define NKT    5        // k-tiles of 32
#define NPH    32       // 16-col phases per block (128 rows x 512 cols)

typedef __bf16  bf16x8 __attribute__((ext_vector_type(8)));
typedef float   f32x4  __attribute__((ext_vector_type(4)));
typedef unsigned short u16x4 __attribute__((ext_vector_type(4)));

// ws layout (bytes)
#define OFF_A    0u
#define OFF_B    (BDIM * K_PAD * 2u)                  // 2,621,440
#define OFF_RS   (2u * BDIM * K_PAD * 2u)             // 5,242,880
#define OFF_CP   (OFF_RS + BDIM * 4u)                 // 4 separated col replicas
#define OFF_DG   (OFF_CP + 4u * BDIM * 4u)

// ---- hardware transcendentals (v_sqrt_f32 / v_log_f32 / v_exp_f32) ----
__device__ __forceinline__ float fast_sqrt(float x) {
#if __has_builtin(__builtin_amdgcn_sqrtf)
    return __builtin_amdgcn_sqrtf(x);
#else
    return sqrtf(x);
#endif
}
__device__ __forceinline__ float fast_log2(float x) {
#if __has_builtin(__builtin_amdgcn_logf)
    return __builtin_amdgcn_logf(x);       // log base 2
#else
    return __log2f(x);
#endif
}
__device__ __forceinline__ float fast_exp2(float x) {
#if __has_builtin(__builtin_amdgcn_exp2f)
    return __builtin_amdgcn_exp2f(x);      // 2^x
#else
    extern "C" __device__ float __ocml_native_exp2_f32(float);
    return __ocml_native_exp2_f32(x);
#endif
}

__device__ __forceinline__ unsigned short f2bf_rne(float f) {
    unsigned int u = __float_as_uint(f);
    u += 0x7FFFu + ((u >> 16) & 1u);   // round-to-nearest-even
    return (unsigned short)(u >> 16);
}

// ---------------------------------------------------------------------------
// Kernel 1: fp32 -> bf16, float4-granular. K zero-padded 129->160, Lorentz
// metric folded into A (negate col 0). Also zeroes row_sum + 4 col replicas.
// ---------------------------------------------------------------------------
__global__ __launch_bounds__(256) void convert_kernel(
    const float* __restrict__ z1, const float* __restrict__ z2,
    unsigned short* __restrict__ A, unsigned short* __restrict__ B,
    float* __restrict__ rs_cp)
{
    int v = blockIdx.x * 256 + threadIdx.x;
    if (v < 5 * BDIM) rs_cp[v] = 0.f;          // rs (8192) + cp (4*8192)
    if (v >= BDIM * (K_PAD / 4)) return;
    int r  = v / (K_PAD / 4);
    int c4 = (v - r * (K_PAD / 4)) * 4;
    u16x4 a, b;
    #pragma unroll
    for (int i = 0; i < 4; ++i) {
        int c = c4 + i;
        float va = 0.f, vb = 0.f;
        if (c < K_IN) {
            va = z1[r * K_IN + c];
            vb = z2[r * K_IN + c];
            if (c == 0) va = -va;              // Lorentz metric on coord 0
        }
        a[i] = f2bf_rne(va);
        b[i] = f2bf_rne(vb);
    }
    *(u16x4*)(A + r * K_PAD + c4) = a;
    *(u16x4*)(B + r * K_PAD + c4) = b;
}

// ---------------------------------------------------------------------------
// Kernel 2: strip-GEMM with fused acosh/exp epilogue; wave-private B tiles,
// per-wave counted-vmcnt pipeline, NO barriers.
//   grid = 1024: bid = chunk*64 + strip
//   block: rows [strip*128, +128) x cols [chunk*512, +512)
//   wave w (0..3): rows [strip*128 + w*32, +32), 32 phases of 16 cols,
//   private LDS double buffer Bs[w][2][16*160].
//   fragment layouts (guide-verified, m89/m91):
//     A/B operand: elem [m=lane&15][k=(lane>>4)*8 + j]
//     C/D:         elem [row=(lane>>4)*4 + reg][col=lane&15]
// ---------------------------------------------------------------------------

// Stage one 16-col B-tile (5120B contiguous global chunk) into THIS WAVE's
// private buffer: 5 async 1KB issues. LDS dest wave-uniform + lane*16 (m104).
#define STAGE16(bufidx, cb)                                                   \
    {                                                                         \
        const char* _gp = (const char*)(B + (size_t)(cb) * K_PAD)             \
                          + lane * 16;                                        \
        char* _lp = (char*)&Bs[wave][bufidx][0];                              \
        _Pragma("unroll")                                                     \
        for (int _m = 0; _m < 5; ++_m)                                        \
            __builtin_amdgcn_global_load_lds(                                 \
                (const __attribute__((address_space(1))) void*)               \
                    (_gp + _m * 1024),                                        \
                (__attribute__((address_space(3))) void*)(_lp + _m * 1024),   \
                16, 0, 0);                                                    \
    }

// MFMA + fused epilogue for one 32x16 wave-tile from the private buffer.
#define COMPUTE16(bufidx, cb)                                                 \
    {                                                                         \
        const int colBase = (cb);                                             \
        const unsigned short* _Bt = &Bs[wave][bufidx][0];                     \
        f32x4 acc[2] = {};                                                    \
        _Pragma("unroll")                                                     \
        for (int kt = 0; kt < NKT; ++kt) {                                    \
            bf16x8 bfr = *(const bf16x8*)                                     \
                &_Bt[l16 * K_PAD + quad * 8 + kt * BK];                       \
            acc[0] = __builtin_amdgcn_mfma_f32_16x16x32_bf16(                 \
                         Ah[0][kt], bfr, acc[0], 0, 0, 0);                    \
            acc[1] = __builtin_amdgcn_mfma_f32_16x16x32_bf16(                 \
                         Ah[1][kt], bfr, acc[1], 0, 0, 0);                    \
        }                                                                     \
        float colp = 0.f;                                                     \
        _Pragma("unroll")                                                     \
        for (int i = 0; i < 2; ++i) {                                         \
            const bool diagTile = (colBase == rowBase + i * 16);              \
            _Pragma("unroll")                                                 \
            for (int reg = 0; reg < 4; ++reg) {                               \
                float inner = acc[i][reg];                                    \
                float x = fmaxf(-inner, 1.000001f);                           \
                float s = fast_sqrt(__builtin_fmaf(x, x, -1.0f));             \
                float l2u = fast_log2(x + s);                                 \
                float e = fast_exp2(-14.285714285714286f * l2u);              \
                rowp[i][reg] += e;                                            \
                colp         += e;                                            \
                if (diagTile && (quad * 4 + reg) == l16) {                    \
                    int R = rowBase + i * 16 + quad * 4 + reg;                \
                    diag[R] = -9.902102579427789f * l2u;                      \
                }                                                             \
            }                                                                 \
        }                                                                     \
        float v = colp;                                                       \
        v += __shfl_xor(v, 16);                                               \
        v += __shfl_xor(v, 32);                                               \
        if (quad == 0)                                                        \
            atomicAdd(&colRep[colBase + l16], v);                             \
    }

__global__ __launch_bounds__(256, 4) void gemm_epilogue_kernel(
    const unsigned short* __restrict__ A, const unsigned short* __restrict__ B,
    float* __restrict__ row_sum, float* __restrict__ col_part,
    float* __restrict__ diag)
{
    const int t    = threadIdx.x;
    const int lane = t & 63;
    const int wave = t >> 6;
    const int quad = lane >> 4;
    const int l16  = lane & 15;

    const int strip = blockIdx.x & 63;
    const int chunk = blockIdx.x >> 6;                // 0..15
    const int rowBase  = strip * 128 + wave * 32;     // wave's first row
    const int colChunk = chunk * 512;                 // block's first col

    const unsigned short* Abase = A + (rowBase + l16) * K_PAD + quad * 8;
    float* colRep = col_part + (strip & 3) * BDIM;    // contention / 4

    // Wave-private B-tile double buffers: 4 x 2 x 16x160 shorts = 40,960B.
    __shared__ __align__(16) unsigned short Bs[4][2][16 * K_PAD];

    // ---- hoist the entire A operand for this wave: 2 row-frags x 5 k-tiles
    bf16x8 Ah[2][NKT];
    #pragma unroll
    for (int i = 0; i < 2; ++i)
        #pragma unroll
        for (int kt = 0; kt < NKT; ++kt)
            Ah[i][kt] = *(const bf16x8*)(Abase + i * 16 * K_PAD + kt * BK);

    float rowp[2][4] = {};   // persistent across all phases

    // ---- per-wave pipeline: NO __syncthreads anywhere ----
    STAGE16(0, colChunk);                 // prologue: phase 0 -> buf 0

    #pragma unroll 1
    for (int ct = 0; ct < NPH; ++ct) {
        if (ct + 1 < NPH) {
            STAGE16((ct + 1) & 1, colChunk + (ct + 1) * 16);
            // Wait until only phase ct+1's 5 loads remain in flight:
            // phase ct's loads (issued one full phase ago) are drained.
            asm volatile("s_waitcnt vmcnt(5)" ::: "memory");
        } else {
            asm volatile("s_waitcnt vmcnt(0)" ::: "memory");
        }
        __builtin_amdgcn_sched_barrier(0);   // rule #18: pin the wait
        COMPUTE16(ct & 1, colChunk + ct * 16);
    }

    // row sums: accumulated over all 32 phases; reduce across the 16 lanes
    // of each quad (they hold the cols), one atomic per row
    #pragma unroll
    for (int i = 0; i < 2; ++i) {
        #pragma unroll
        for (int reg = 0; reg < 4; ++reg) {
            float v = rowp[i][reg];
            v += __shfl_xor(v, 1);
            v += __shfl_xor(v, 2);
            v += __shfl_xor(v, 4);
            v += __shfl_xor(v, 8);
            if (l16 == 0)
                atomicAdd(&row_sum[rowBase + i * 16 + quad * 4 + reg], v);
        }
    }
}

// ---------------------------------------------------------------------------
// Kernel 3: loss = mean_b( 0.5*(ln rs[b] + ln cs[b]) - diag[b] ),
// cs[b] = sum of 4 separated replicas.
// ---------------------------------------------------------------------------
__global__ __launch_bounds__(1024) void finalize_kernel(
    const float* __restrict__ rs, const float* __restrict__ cp,
    const float* __restrict__ dg, float* __restrict__ out)
{
    __shared__ float part[16];
    int t = threadIdx.x;
    float a = 0.f;
    const float LN2_HALF = 0.34657359027997264f;  // 0.5 * ln2
    for (int b = t; b < BDIM; b += 1024) {
        float cs = cp[b] + cp[b + BDIM] + cp[b + 2 * BDIM] + cp[b + 3 * BDIM];
        a += LN2_HALF * (fast_log2(rs[b]) + fast_log2(cs)) - dg[b];
    }
    #pragma unroll
    for (int m = 1; m < 64; m <<= 1) a += __shfl_xor(a, m);
    if ((t & 63) == 0) part[t >> 6] = a;
    __syncthreads();
    if (t < 16) {
        float v = part[t];
        #pragma unroll
        for (int m = 1; m < 16; m <<= 1) v += __shfl_xor(v, m);
        if (t == 0) out[0] = v * (1.0f / (float)BDIM);
    }
}

// ---------------------------------------------------------------------------
extern "C" void kernel_launch(void* const* d_in, const int* in_sizes, int n_in,
                              void* d_out, int out_size, void* d_ws, size_t ws_size,
                              hipStream_t stream)
{
    const float* z1 = (const float*)d_in[0];
    const float* z2 = (const float*)d_in[1];
    float* out = (float*)d_out;

    char* ws = (char*)d_ws;
    unsigned short* A  = (unsigned short*)(ws + OFF_A);
    unsigned short* B  = (unsigned short*)(ws + OFF_B);
    float* row_sum     = (float*)(ws + OFF_RS);
    float* col_part    = (float*)(ws + OFF_CP);
    float* diag        = (float*)(ws + OFF_DG);

    convert_kernel<<<(BDIM * (K_PAD / 4) + 255) / 256, 256, 0, stream>>>(
        z1, z2, A, B, row_sum /* rs + 4 separated col replicas contiguous */);

    gemm_epilogue_kernel<<<1024, 256, 0, stream>>>(
        A, B, row_sum, col_part, diag);

    finalize_kernel<<<1, 1024, 0, stream>>>(row_sum, col_part, diag, out);
}